// Round 16
// baseline (7192.838 us; speedup 1.0000x reference)
//
#include <hip/hip_runtime.h>
#include <math.h>

// LSTMModel: 2048 sequential steps, 2x LSTMCell(H=512), LN(64) front, fc(512->1).
// R15 = R14 (4.99ms) + L1 restructured EXACTLY like L0: 64 blocks x 8 units,
// 2 rows/lane-group, unit=wave -> gate exchange in-wave (shfl), biases pre-shuffled
// to lane-0 regs => deletes L1's glds LDS exchange + 2nd barrier from the h1
// self-chain. Bonus: 64 publisher blocks (straggler max over 64 not 128 packets),
// half the L1 poll streams. L1 weights 64 f32/thread (w1[2][16]+w2[2][16]) --
// between proven-resident 32 (R9) and failed 128 (R6-8); R10 held 48 fine.

#define H      512
#define G4     2048
#define WIN    64
#define STEPS  2048
#define NL0B   64      // layer-0 blocks (8 units each)
#define NL1B   64      // layer-1 blocks (8 units each)
#define TPB    512
#define POISON 0xFFFFFFFFu

typedef unsigned int u32x4 __attribute__((ext_vector_type(4)));
typedef float        f32x4 __attribute__((ext_vector_type(4)));

__device__ __forceinline__ float sigf(float x)     { return 1.0f / (1.0f + __expf(-x)); }
__device__ __forceinline__ float tanhfast(float x) { return 2.0f / (1.0f + __expf(-2.0f * x)) - 1.0f; }

// ---- agent-scope helpers (issue+wait in ONE asm block -> sound) ----
__device__ __forceinline__ u32x4 ld4_sc01(const unsigned int* p) {
    u32x4 v;
    asm volatile("global_load_dwordx4 %0, %1, off sc0 sc1\n\ts_waitcnt vmcnt(0)"
                 : "=&v"(v) : "v"(p));
    return v;
}
// dual-packet load: both in flight together, one wait -> 1 RTT for the pair
__device__ __forceinline__ void ld4x2_sc01(const unsigned int* pa, const unsigned int* pb,
                                           u32x4& va, u32x4& vb) {
    asm volatile("global_load_dwordx4 %0, %2, off sc0 sc1\n\t"
                 "global_load_dwordx4 %1, %3, off sc0 sc1\n\t"
                 "s_waitcnt vmcnt(0)"
                 : "=&v"(va), "=&v"(vb) : "v"(pa), "v"(pb));
}
__device__ __forceinline__ void st1_sc01(unsigned int* p, unsigned int v) {
    asm volatile("global_store_dword %0, %1, off sc0 sc1" :: "v"(p), "v"(v));
}
__device__ __forceinline__ bool ok4(u32x4 v) {
    return v.x != POISON && v.y != POISON && v.z != POISON && v.w != POISON;
}
__device__ __forceinline__ void lds_put4(float* dst, u32x4 v) {
    float4 f;
    f.x = __uint_as_float(v.x); f.y = __uint_as_float(v.y);
    f.z = __uint_as_float(v.z); f.w = __uint_as_float(v.w);
    *(float4*)dst = f;
}

// ---------------- LayerNorm over sliding windows (parallel over t) ----------------
__global__ void ln_kernel(const float* __restrict__ batch, const float* __restrict__ lnw,
                          const float* __restrict__ lnb, float* __restrict__ lnx) {
    int wave = threadIdx.x >> 6;
    int lane = threadIdx.x & 63;
    int t = blockIdx.x * 4 + wave;
    int src = t - 63 + lane;
    float v = (src >= 0) ? batch[src] : 0.0f;
    float s = v, ss = v * v;
    #pragma unroll
    for (int m = 32; m >= 1; m >>= 1) { s += __shfl_xor(s, m); ss += __shfl_xor(ss, m); }
    float mu   = s * (1.0f / 64.0f);
    float var  = ss * (1.0f / 64.0f) - mu * mu;
    float rstd = rsqrtf(var + 1e-5f);
    lnx[t * WIN + lane] = (v - mu) * rstd * lnw[lane] + lnb[lane];
}

// ---- precomp, UNIT-MAJOR layout: pre[t*2048 + unit*4 + gate] ----
__global__ __launch_bounds__(256) void precomp_kernel(
    const float* __restrict__ Wih0, const float* __restrict__ bih0,
    const float* __restrict__ bhh0, const float* __restrict__ lnx,
    float* __restrict__ pre) {
    __shared__ float Wt[64][65];
    __shared__ float Xt[64][64];
    int r0 = blockIdx.x * 64;
    int t0 = blockIdx.y * 64;
    for (int i = threadIdx.x; i < 4096; i += 256) Wt[i >> 6][i & 63] = Wih0[r0 * 64 + i];
    for (int i = threadIdx.x; i < 4096; i += 256) Xt[i >> 6][i & 63] = lnx[t0 * 64 + i];
    __syncthreads();
    int lane = threadIdx.x & 63;
    int wv   = threadIdx.x >> 6;
    int row  = r0 + lane;                      // gate-major: gate*512 + unit
    int oidx = (row & 511) * 4 + (row >> 9);   // unit-major: unit*4 + gate
    float bias = bih0[row] + bhh0[row];
    for (int j = 0; j < 16; ++j) {
        int tl = wv * 16 + j;
        float acc = bias;
        #pragma unroll 8
        for (int k = 0; k < 64; ++k) acc += Wt[lane][k] * Xt[tl][k];
        pre[(size_t)(t0 + tl) * G4 + oidx] = acc;
    }
}

// ---------------- persistent recurrent kernel ----------------
__global__ __launch_bounds__(TPB) void recur_kernel(
    const float* __restrict__ Whh0,
    const float* __restrict__ Wih1, const float* __restrict__ Whh1,
    const float* __restrict__ bih1, const float* __restrict__ bhh1,
    const float* __restrict__ pre,
    unsigned int* h0u, unsigned int* h1u) { // [STEPS+1][H] histories, NaN-poisoned
    const int tid = threadIdx.x;
    const int s   = tid & 31;
    const int LG  = tid >> 5;    // 16 lane-groups of 32
    const int uw  = tid >> 6;    // wave index = unit-local (both layers)

    if (blockIdx.x < NL0B) {
        // -------- layer-0: 8 units/block; unit = wave; 2 rows/lane-group --------
        __shared__ float hA[2][H];
        const int u0 = blockIdx.x * 8;
        float w0[2][16];
        #pragma unroll
        for (int j = 0; j < 2; ++j) {
            int r   = 2 * LG + j;
            int row = (r & 3) * H + u0 + (r >> 2);
            #pragma unroll
            for (int i = 0; i < 16; ++i) w0[j][i] = Whh0[(size_t)row * H + i * 32 + s];
        }
        float c0 = 0.0f;

        for (int t = 0; t < STEPS; ++t) {
            const int pb = t & 1;
            // pre for this wave's unit (wave-uniform broadcast load; hides under poll)
            f32x4 prv = *(const f32x4*)(pre + (size_t)t * G4 + (u0 + uw) * 4);
            if (tid < 128) {
                if (t > 0) {
                    const unsigned int* p = h0u + (size_t)t * H + tid * 4;
                    u32x4 v;
                    do { v = ld4_sc01(p); } while (!ok4(v));
                    lds_put4(&hA[pb][tid * 4], v);
                } else {
                    *(float4*)&hA[pb][tid * 4] = make_float4(0.f, 0.f, 0.f, 0.f);
                }
            }
            __syncthreads();

            float acc0 = 0.0f, acc1 = 0.0f;
            #pragma unroll
            for (int i = 0; i < 16; ++i) {
                float hv = hA[pb][i * 32 + s];
                acc0 += w0[0][i] * hv;
                acc1 += w0[1][i] * hv;
            }
            #pragma unroll
            for (int m = 16; m >= 1; m >>= 1) {
                acc0 += __shfl_xor(acc0, m);
                acc1 += __shfl_xor(acc1, m);
            }
            // lower half-wave group: gates i,f ; upper (lane 32): g,o
            float gacc = __shfl(acc0, 32);
            float oacc = __shfl(acc1, 32);
            if ((tid & 63) == 0) {
                float iv = sigf(acc0 + prv.x);
                float fv = sigf(acc1 + prv.y);
                float gv = tanhfast(gacc + prv.z);
                float ov = sigf(oacc + prv.w);
                c0 = fv * c0 + iv * gv;
                float hnew = ov * tanhfast(c0);
                st1_sc01(h0u + (size_t)(t + 1) * H + u0 + uw, __float_as_uint(hnew));
            }
        }
    } else {
        // -------- layer-1: 8 units/block; unit = wave; 2 rows/lane-group;
        //          in-wave gate exchange (NO glds, ONE barrier per step) --------
        __shared__ float hA2[2][H];
        __shared__ float hB2[2][H];
        const int u0 = (blockIdx.x - NL0B) * 8;
        float w1[2][16], w2[2][16], bias[2];
        #pragma unroll
        for (int j = 0; j < 2; ++j) {
            int r   = 2 * LG + j;
            int row = (r & 3) * H + u0 + (r >> 2);
            bias[j] = bih1[row] + bhh1[row];
            #pragma unroll
            for (int i = 0; i < 16; ++i) {
                w1[j][i] = Wih1[(size_t)row * H + i * 32 + s];
                w2[j][i] = Whh1[(size_t)row * H + i * 32 + s];
            }
        }
        // pre-shuffle gate biases into lane-0 registers (loop-invariant)
        const float b_i = bias[0];
        const float b_f = bias[1];
        const float b_g = __shfl(bias[0], 32);
        const float b_o = __shfl(bias[1], 32);
        float c1 = 0.0f;

        for (int t = 0; t < STEPS; ++t) {
            const int pb = t & 1;
            if (tid < 128) {
                const unsigned int* pa = h0u + (size_t)(t + 1) * H + tid * 4;
                if (t > 0) {
                    // DUAL poll: h0 feed + h1 self-chain in flight together, one wait
                    const unsigned int* pbp = h1u + (size_t)t * H + tid * 4;
                    u32x4 va, vb;
                    do { ld4x2_sc01(pa, pbp, va, vb); } while (!(ok4(va) && ok4(vb)));
                    lds_put4(&hA2[pb][tid * 4], va);
                    lds_put4(&hB2[pb][tid * 4], vb);
                } else {
                    u32x4 va;
                    do { va = ld4_sc01(pa); } while (!ok4(va));
                    lds_put4(&hA2[pb][tid * 4], va);
                    *(float4*)&hB2[pb][tid * 4] = make_float4(0.f, 0.f, 0.f, 0.f);
                }
            }
            __syncthreads();

            float acc0 = 0.0f, acc1 = 0.0f;
            #pragma unroll
            for (int i = 0; i < 16; ++i) {
                float xa = hA2[pb][i * 32 + s];
                float xb = hB2[pb][i * 32 + s];
                acc0 += w1[0][i] * xa + w2[0][i] * xb;
                acc1 += w1[1][i] * xa + w2[1][i] * xb;
            }
            #pragma unroll
            for (int m = 16; m >= 1; m >>= 1) {
                acc0 += __shfl_xor(acc0, m);
                acc1 += __shfl_xor(acc1, m);
            }
            float gacc = __shfl(acc0, 32);
            float oacc = __shfl(acc1, 32);
            if ((tid & 63) == 0) {
                float iv = sigf(acc0 + b_i);
                float fv = sigf(acc1 + b_f);
                float gv = tanhfast(gacc + b_g);
                float ov = sigf(oacc + b_o);
                c1 = fv * c1 + iv * gv;
                float hnew = ov * tanhfast(c1);
                st1_sc01(h1u + (size_t)(t + 1) * H + u0 + uw, __float_as_uint(hnew));
            }
        }
    }
}

// ---------------- out[t] = fc(relu(h1[t+1])) from the h1 history ----------------
__global__ __launch_bounds__(TPB) void reduce_out(
    const unsigned int* __restrict__ h1u, const float* __restrict__ fcw,
    const float* __restrict__ fcb, float* __restrict__ out) {
    int t = blockIdx.x;
    int tid = threadIdx.x;               // 512 threads
    float h = __uint_as_float(h1u[(size_t)(t + 1) * H + tid]);
    float v = fmaxf(h, 0.0f) * fcw[tid];
    #pragma unroll
    for (int m = 32; m >= 1; m >>= 1) v += __shfl_xor(v, m);
    __shared__ float ws8[8];
    if ((tid & 63) == 0) ws8[tid >> 6] = v;
    __syncthreads();
    if (tid == 0) {
        float ssum = 0.0f;
        #pragma unroll
        for (int i = 0; i < 8; ++i) ssum += ws8[i];
        out[t] = ssum + fcb[0];
    }
}

extern "C" void kernel_launch(void* const* d_in, const int* in_sizes, int n_in,
                              void* d_out, int out_size, void* d_ws, size_t ws_size,
                              hipStream_t stream) {
    const float* batch = (const float*)d_in[0];
    const float* Wih0  = (const float*)d_in[1];
    const float* Whh0  = (const float*)d_in[2];
    const float* bih0  = (const float*)d_in[3];
    const float* bhh0  = (const float*)d_in[4];
    const float* Wih1  = (const float*)d_in[5];
    const float* Whh1  = (const float*)d_in[6];
    const float* bih1  = (const float*)d_in[7];
    const float* bhh1  = (const float*)d_in[8];
    const float* lnw   = (const float*)d_in[9];
    const float* lnb   = (const float*)d_in[10];
    const float* fcw   = (const float*)d_in[11];
    const float* fcb   = (const float*)d_in[12];
    float* out = (float*)d_out;

    // workspace layout (~17 MB)
    float*        ws   = (float*)d_ws;
    float*        pre  = ws;                                   // 2048*2048 (16 MB)
    float*        lnx  = pre + (size_t)STEPS * G4;             // 2048*64
    unsigned int* h0u  = (unsigned int*)(lnx + (size_t)STEPS * WIN);  // 2049*512
    unsigned int* h1u  = h0u + (size_t)(STEPS + 1) * H;        // 2049*512

    // poison both h histories (NaN pattern); slot 0 handled by t==0 branch in-kernel
    (void)hipMemsetAsync(h0u, 0xFF, (size_t)2 * (STEPS + 1) * H * sizeof(unsigned int), stream);

    ln_kernel<<<dim3(STEPS / 4), dim3(256), 0, stream>>>(batch, lnw, lnb, lnx);
    precomp_kernel<<<dim3(G4 / 64, STEPS / 64), dim3(256), 0, stream>>>(Wih0, bih0, bhh0, lnx, pre);
    recur_kernel<<<dim3(NL0B + NL1B), dim3(TPB), 0, stream>>>(Whh0, Wih1, Whh1, bih1, bhh1,
                                                              pre, h0u, h1u);
    reduce_out<<<dim3(STEPS), dim3(TPB), 0, stream>>>(h1u, fcw, fcb, out);
}

// Round 17
// 5075.972 us; speedup vs baseline: 1.4170x; 1.4170x over previous
//
#include <hip/hip_runtime.h>
#include <math.h>

// LSTMModel: 2048 sequential steps, 2x LSTMCell(H=512), LN(64) front, fc(512->1).
// R16 = R14 REVERT (best: 4.99ms; R15's 64-w/thread L1 crossed the residency cliff,
// VGPR 52 < 64 -> restream, 7.2ms) + atomic packed h1 publish: lanes 0-3 of wave 0
// shfl-gather the 4 unit h values into ONE st4 -> consumer's h1 packet appears
// atomically (no intra-packet skew on the critical h1 self-chain).
// Residency ledger: <=48 f32/thread resident (R10), >=64 restreams (R15).

#define H      512
#define G4     2048
#define WIN    64
#define STEPS  2048
#define NL0B   64      // layer-0 blocks (8 units each)
#define NL1B   128     // layer-1 blocks (4 units each)
#define TPB    512
#define POISON 0xFFFFFFFFu

typedef unsigned int u32x4 __attribute__((ext_vector_type(4)));
typedef float        f32x4 __attribute__((ext_vector_type(4)));

__device__ __forceinline__ float sigf(float x)     { return 1.0f / (1.0f + __expf(-x)); }
__device__ __forceinline__ float tanhfast(float x) { return 2.0f / (1.0f + __expf(-2.0f * x)) - 1.0f; }

// ---- agent-scope helpers (issue+wait in ONE asm block -> sound) ----
__device__ __forceinline__ u32x4 ld4_sc01(const unsigned int* p) {
    u32x4 v;
    asm volatile("global_load_dwordx4 %0, %1, off sc0 sc1\n\ts_waitcnt vmcnt(0)"
                 : "=&v"(v) : "v"(p));
    return v;
}
// dual-packet load: both in flight together, one wait -> 1 RTT for the pair
__device__ __forceinline__ void ld4x2_sc01(const unsigned int* pa, const unsigned int* pb,
                                           u32x4& va, u32x4& vb) {
    asm volatile("global_load_dwordx4 %0, %2, off sc0 sc1\n\t"
                 "global_load_dwordx4 %1, %3, off sc0 sc1\n\t"
                 "s_waitcnt vmcnt(0)"
                 : "=&v"(va), "=&v"(vb) : "v"(pa), "v"(pb));
}
__device__ __forceinline__ void st1_sc01(unsigned int* p, unsigned int v) {
    asm volatile("global_store_dword %0, %1, off sc0 sc1" :: "v"(p), "v"(v));
}
__device__ __forceinline__ void st4_sc01(unsigned int* p, u32x4 v) {
    asm volatile("global_store_dwordx4 %0, %1, off sc0 sc1" :: "v"(p), "v"(v));
}
__device__ __forceinline__ bool ok4(u32x4 v) {
    return v.x != POISON && v.y != POISON && v.z != POISON && v.w != POISON;
}
__device__ __forceinline__ void lds_put4(float* dst, u32x4 v) {
    float4 f;
    f.x = __uint_as_float(v.x); f.y = __uint_as_float(v.y);
    f.z = __uint_as_float(v.z); f.w = __uint_as_float(v.w);
    *(float4*)dst = f;
}

// ---------------- LayerNorm over sliding windows (parallel over t) ----------------
__global__ void ln_kernel(const float* __restrict__ batch, const float* __restrict__ lnw,
                          const float* __restrict__ lnb, float* __restrict__ lnx) {
    int wave = threadIdx.x >> 6;
    int lane = threadIdx.x & 63;
    int t = blockIdx.x * 4 + wave;
    int src = t - 63 + lane;
    float v = (src >= 0) ? batch[src] : 0.0f;
    float s = v, ss = v * v;
    #pragma unroll
    for (int m = 32; m >= 1; m >>= 1) { s += __shfl_xor(s, m); ss += __shfl_xor(ss, m); }
    float mu   = s * (1.0f / 64.0f);
    float var  = ss * (1.0f / 64.0f) - mu * mu;
    float rstd = rsqrtf(var + 1e-5f);
    lnx[t * WIN + lane] = (v - mu) * rstd * lnw[lane] + lnb[lane];
}

// ---- precomp, UNIT-MAJOR layout: pre[t*2048 + unit*4 + gate] ----
__global__ __launch_bounds__(256) void precomp_kernel(
    const float* __restrict__ Wih0, const float* __restrict__ bih0,
    const float* __restrict__ bhh0, const float* __restrict__ lnx,
    float* __restrict__ pre) {
    __shared__ float Wt[64][65];
    __shared__ float Xt[64][64];
    int r0 = blockIdx.x * 64;
    int t0 = blockIdx.y * 64;
    for (int i = threadIdx.x; i < 4096; i += 256) Wt[i >> 6][i & 63] = Wih0[r0 * 64 + i];
    for (int i = threadIdx.x; i < 4096; i += 256) Xt[i >> 6][i & 63] = lnx[t0 * 64 + i];
    __syncthreads();
    int lane = threadIdx.x & 63;
    int wv   = threadIdx.x >> 6;
    int row  = r0 + lane;                      // gate-major: gate*512 + unit
    int oidx = (row & 511) * 4 + (row >> 9);   // unit-major: unit*4 + gate
    float bias = bih0[row] + bhh0[row];
    for (int j = 0; j < 16; ++j) {
        int tl = wv * 16 + j;
        float acc = bias;
        #pragma unroll 8
        for (int k = 0; k < 64; ++k) acc += Wt[lane][k] * Xt[tl][k];
        pre[(size_t)(t0 + tl) * G4 + oidx] = acc;
    }
}

// ---------------- persistent recurrent kernel ----------------
__global__ __launch_bounds__(TPB) void recur_kernel(
    const float* __restrict__ Whh0,
    const float* __restrict__ Wih1, const float* __restrict__ Whh1,
    const float* __restrict__ bih1, const float* __restrict__ bhh1,
    const float* __restrict__ pre,
    unsigned int* h0u, unsigned int* h1u) { // [STEPS+1][H] histories, NaN-poisoned
    const int tid = threadIdx.x;
    const int s   = tid & 31;
    const int LG  = tid >> 5;    // 16 lane-groups of 32

    if (blockIdx.x < NL0B) {
        // -------- layer-0: 8 units/block; unit = wave; 2 rows/lane-group --------
        __shared__ float hA[2][H];
        const int u0 = blockIdx.x * 8;
        const int u  = tid >> 6;              // wave index = unit-local
        float w0[2][16];
        #pragma unroll
        for (int j = 0; j < 2; ++j) {
            int r   = 2 * LG + j;
            int row = (r & 3) * H + u0 + (r >> 2);
            #pragma unroll
            for (int i = 0; i < 16; ++i) w0[j][i] = Whh0[(size_t)row * H + i * 32 + s];
        }
        float c0 = 0.0f;

        for (int t = 0; t < STEPS; ++t) {
            const int pb = t & 1;
            // pre for this wave's unit (wave-uniform broadcast load; hides under poll)
            f32x4 prv = *(const f32x4*)(pre + (size_t)t * G4 + (u0 + u) * 4);
            if (tid < 128) {
                if (t > 0) {
                    const unsigned int* p = h0u + (size_t)t * H + tid * 4;
                    u32x4 v;
                    do { v = ld4_sc01(p); } while (!ok4(v));
                    lds_put4(&hA[pb][tid * 4], v);
                } else {
                    *(float4*)&hA[pb][tid * 4] = make_float4(0.f, 0.f, 0.f, 0.f);
                }
            }
            __syncthreads();

            float acc0 = 0.0f, acc1 = 0.0f;
            #pragma unroll
            for (int i = 0; i < 16; ++i) {
                float hv = hA[pb][i * 32 + s];
                acc0 += w0[0][i] * hv;
                acc1 += w0[1][i] * hv;
            }
            #pragma unroll
            for (int m = 16; m >= 1; m >>= 1) {
                acc0 += __shfl_xor(acc0, m);
                acc1 += __shfl_xor(acc1, m);
            }
            // lower half-wave group: gates i,f ; upper (lane 32): g,o
            float gacc = __shfl(acc0, 32);
            float oacc = __shfl(acc1, 32);
            if ((tid & 63) == 0) {
                float iv = sigf(acc0 + prv.x);
                float fv = sigf(acc1 + prv.y);
                float gv = tanhfast(gacc + prv.z);
                float ov = sigf(oacc + prv.w);
                c0 = fv * c0 + iv * gv;
                float hnew = ov * tanhfast(c0);
                st1_sc01(h0u + (size_t)(t + 1) * H + u0 + u, __float_as_uint(hnew));
            }
        }
    } else {
        // -------- layer-1: 4 units/block; 1 row/lane-group; LDS gate exchange --------
        __shared__ float hA2[2][H];
        __shared__ float hB2[2][H];
        __shared__ float glds[16];
        const int b1 = blockIdx.x - NL0B;
        const int u0 = b1 * 4;
        const int row = (LG & 3) * H + u0 + (LG >> 2);
        float w1[16], w2[16];
        #pragma unroll
        for (int i = 0; i < 16; ++i) {
            w1[i] = Wih1[(size_t)row * H + i * 32 + s];
            w2[i] = Whh1[(size_t)row * H + i * 32 + s];
        }
        const float rbias = bih1[row] + bhh1[row];
        float c1 = 0.0f;

        for (int t = 0; t < STEPS; ++t) {
            const int pb = t & 1;
            if (tid < 128) {
                const unsigned int* pa = h0u + (size_t)(t + 1) * H + tid * 4;
                if (t > 0) {
                    // DUAL poll: h0 feed + h1 self-chain in flight together, one wait
                    const unsigned int* pbp = h1u + (size_t)t * H + tid * 4;
                    u32x4 va, vb;
                    do { ld4x2_sc01(pa, pbp, va, vb); } while (!(ok4(va) && ok4(vb)));
                    lds_put4(&hA2[pb][tid * 4], va);
                    lds_put4(&hB2[pb][tid * 4], vb);
                } else {
                    u32x4 va;
                    do { va = ld4_sc01(pa); } while (!ok4(va));
                    lds_put4(&hA2[pb][tid * 4], va);
                    *(float4*)&hB2[pb][tid * 4] = make_float4(0.f, 0.f, 0.f, 0.f);
                }
            }
            __syncthreads();

            float acc = 0.0f;
            #pragma unroll
            for (int i = 0; i < 16; ++i)
                acc += w1[i] * hA2[pb][i * 32 + s] + w2[i] * hB2[pb][i * 32 + s];
            #pragma unroll
            for (int m = 16; m >= 1; m >>= 1) acc += __shfl_xor(acc, m);
            if (s == 0) glds[LG] = acc + rbias;
            __syncthreads();

            float hnew = 0.0f;
            if (tid < 4) {
                float iv = sigf(glds[4 * tid + 0]);
                float fv = sigf(glds[4 * tid + 1]);
                float gv = tanhfast(glds[4 * tid + 2]);
                float ov = sigf(glds[4 * tid + 3]);
                c1 = fv * c1 + iv * gv;
                hnew = ov * tanhfast(c1);
            }
            // ATOMIC packed publish: lanes 0-3 (wave 0) gathered into one st4
            if (tid < 64) {
                unsigned int hb = __float_as_uint(hnew);
                u32x4 pk;
                pk.x = __shfl(hb, 0); pk.y = __shfl(hb, 1);
                pk.z = __shfl(hb, 2); pk.w = __shfl(hb, 3);
                if (tid == 0)
                    st4_sc01(h1u + (size_t)(t + 1) * H + u0, pk);
            }
        }
    }
}

// ---------------- out[t] = fc(relu(h1[t+1])) from the h1 history ----------------
__global__ __launch_bounds__(TPB) void reduce_out(
    const unsigned int* __restrict__ h1u, const float* __restrict__ fcw,
    const float* __restrict__ fcb, float* __restrict__ out) {
    int t = blockIdx.x;
    int tid = threadIdx.x;               // 512 threads
    float h = __uint_as_float(h1u[(size_t)(t + 1) * H + tid]);
    float v = fmaxf(h, 0.0f) * fcw[tid];
    #pragma unroll
    for (int m = 32; m >= 1; m >>= 1) v += __shfl_xor(v, m);
    __shared__ float ws8[8];
    if ((tid & 63) == 0) ws8[tid >> 6] = v;
    __syncthreads();
    if (tid == 0) {
        float ssum = 0.0f;
        #pragma unroll
        for (int i = 0; i < 8; ++i) ssum += ws8[i];
        out[t] = ssum + fcb[0];
    }
}

extern "C" void kernel_launch(void* const* d_in, const int* in_sizes, int n_in,
                              void* d_out, int out_size, void* d_ws, size_t ws_size,
                              hipStream_t stream) {
    const float* batch = (const float*)d_in[0];
    const float* Wih0  = (const float*)d_in[1];
    const float* Whh0  = (const float*)d_in[2];
    const float* bih0  = (const float*)d_in[3];
    const float* bhh0  = (const float*)d_in[4];
    const float* Wih1  = (const float*)d_in[5];
    const float* Whh1  = (const float*)d_in[6];
    const float* bih1  = (const float*)d_in[7];
    const float* bhh1  = (const float*)d_in[8];
    const float* lnw   = (const float*)d_in[9];
    const float* lnb   = (const float*)d_in[10];
    const float* fcw   = (const float*)d_in[11];
    const float* fcb   = (const float*)d_in[12];
    float* out = (float*)d_out;

    // workspace layout (~17 MB)
    float*        ws   = (float*)d_ws;
    float*        pre  = ws;                                   // 2048*2048 (16 MB)
    float*        lnx  = pre + (size_t)STEPS * G4;             // 2048*64
    unsigned int* h0u  = (unsigned int*)(lnx + (size_t)STEPS * WIN);  // 2049*512
    unsigned int* h1u  = h0u + (size_t)(STEPS + 1) * H;        // 2049*512

    // poison both h histories (NaN pattern); slot 0 handled by t==0 branch in-kernel
    (void)hipMemsetAsync(h0u, 0xFF, (size_t)2 * (STEPS + 1) * H * sizeof(unsigned int), stream);

    ln_kernel<<<dim3(STEPS / 4), dim3(256), 0, stream>>>(batch, lnw, lnb, lnx);
    precomp_kernel<<<dim3(G4 / 64, STEPS / 64), dim3(256), 0, stream>>>(Wih0, bih0, bhh0, lnx, pre);
    recur_kernel<<<dim3(NL0B + NL1B), dim3(TPB), 0, stream>>>(Whh0, Wih1, Whh1, bih1, bhh1,
                                                              pre, h0u, h1u);
    reduce_out<<<dim3(STEPS), dim3(TPB), 0, stream>>>(h1u, fcw, fcb, out);
}